// Round 6
// baseline (132.972 us; speedup 1.0000x reference)
//
#include <hip/hip_runtime.h>
#include <math.h>

#define B_  8192
#define F_  256
#define T_  32
#define NI_ 63
#define NL_ 64
#define C_  100
#define K2_ (T_*NL_)       // 2048 = GEMM2 K
#define NG  8              // tree groups
#define TPG 4              // trees per group

typedef unsigned short u16;
typedef __attribute__((ext_vector_type(8))) short bf16x8;   // MFMA A/B frag
typedef __attribute__((ext_vector_type(4))) float f32x4;    // MFMA C/D frag
typedef __attribute__((ext_vector_type(8))) unsigned short u16x8;

__device__ __forceinline__ u16 f2bf(float f) {
    unsigned int u = __float_as_uint(f);
    u += 0x7fffu + ((u >> 16) & 1u);      // RNE
    return (u16)(u >> 16);
}
__device__ __forceinline__ float bf2f(u16 u) {
    return __uint_as_float(((unsigned int)u) << 16);
}

// 16B global->LDS direct copy. LDS dest is WAVE-UNIFORM base (HW adds lane*16);
// global src is per-lane.
__device__ __forceinline__ void gl16(const void* g, void* l) {
    __builtin_amdgcn_global_load_lds(
        (const __attribute__((address_space(1))) unsigned int*)g,
        (__attribute__((address_space(3))) unsigned int*)l,
        16, 0, 0);
}

// ws layout (bytes):
//   swb2 : u16 [T_][32][64][8]  = 1,048,576   (frag-contiguous, n padded to 64)
//   lcp2 : u16 [T_][8][112][8]  =   458,752   (exact LDS tile image per tree)
//   xb   : u16 [B_][F_]         = 4,194,304
//   part : u16 [NG][B_][112]    = 14,680,064  (bf16 partials, store path)
#define WSB_SWB   0
#define WSB_LCPT  (T_*32*64*8*2)                            //  1,048,576
#define WSB_XB    (WSB_LCPT + T_*8*112*8*2)                 //  1,507,328
#define WSB_PART  ((size_t)WSB_XB + (size_t)B_*F_*2)        //  5,701,632
#define WSB_ATOM  WSB_PART                                   // atomic path total
#define WSB_STORE (WSB_PART + (size_t)NG*B_*112*2)           // 20,381,696

// ---- prep: sw -> swb2 [t][k8][64][8], x->bf16, ll -> lcp2 (+ zero section) ----
#define SWBLK  (T_*64*32/256)     // 256 blocks: (t,n,k8) with n padded to 64
#define XBLK   (B_*F_/2048)       // 1024
#define LCPBLK (T_*NL_/256)       // 8
#define ZBLK   (B_*C_/256)        // 3200

__device__ __forceinline__ void cvt8(const float* __restrict__ s, u16* __restrict__ d, int i) {
    const float4* p = (const float4*)(s + i);
    float4 v0 = p[0], v1 = p[1];
    u16x8 o;
    o[0] = f2bf(v0.x); o[1] = f2bf(v0.y); o[2] = f2bf(v0.z); o[3] = f2bf(v0.w);
    o[4] = f2bf(v1.x); o[5] = f2bf(v1.y); o[6] = f2bf(v1.z); o[7] = f2bf(v1.w);
    *(u16x8*)(d + i) = o;
}

__global__ void k_prep(const float* __restrict__ sw, const float* __restrict__ x,
                       const float* __restrict__ ll, const float* __restrict__ tw,
                       const float* __restrict__ logT,
                       u16* __restrict__ swb, u16* __restrict__ xb,
                       u16* __restrict__ lcpT, float* __restrict__ out) {
    int blk = blockIdx.x, tid = threadIdx.x;
    if (blk < SWBLK) {
        // gid -> (t, n(0..63), k8(0..31)); read sw[t][n][k8*8..+8], write
        // swb2[((t*32+k8)*64+n)*8..+8]; n==63 is the pad row (zeros).
        int gid = blk * 256 + tid;
        int k8 = gid & 31;
        int n  = (gid >> 5) & 63;
        int t  = gid >> 11;
        u16x8 o;
        if (n < NI_) {
            const float4* p = (const float4*)(sw + ((size_t)(t * NI_ + n)) * F_ + k8 * 8);
            float4 v0 = p[0], v1 = p[1];
            o[0] = f2bf(v0.x); o[1] = f2bf(v0.y); o[2] = f2bf(v0.z); o[3] = f2bf(v0.w);
            o[4] = f2bf(v1.x); o[5] = f2bf(v1.y); o[6] = f2bf(v1.z); o[7] = f2bf(v1.w);
        } else {
            o = (u16x8){0,0,0,0,0,0,0,0};
        }
        *(u16x8*)(swb + (((size_t)t * 32 + k8) * 64 + n) * 8) = o;
        return;
    }
    blk -= SWBLK;
    if (blk < XBLK) { cvt8(x, xb, blk * 2048 + tid * 8); return; }
    blk -= XBLK;
    if (blk >= LCPBLK) {                    // zero section (atomic path only)
        out[(blk - LCPBLK) * 256 + tid] = 0.f;
        return;
    }
    int idx = blk * 256 + tid;              // leaf row: t*64 + l
    int t = idx >> 6;
    int l = idx & 63;
    int o = l >> 3, jj = l & 7;
    float temp = __expf(logT[0]);
    temp = fminf(fmaxf(temp, 0.1f), 5.0f);
    float invt = 1.0f / temp;

    float m = -1e30f;
    for (int j = 0; j < T_; ++j) m = fmaxf(m, tw[j]);
    float s = 0.f;
    for (int j = 0; j < T_; ++j) s += __expf(tw[j] - m);
    float wt = __expf(tw[t] - m) / s;

    const float* row = ll + (size_t)idx * C_;
    float m2 = -1e30f;
    for (int c = 0; c < C_; ++c) m2 = fmaxf(m2, row[c]);
    float s2 = 0.f;
    for (int c = 0; c < C_; ++c) s2 += __expf((row[c] - m2) * invt);
    float sc = wt / s2;
    u16* base = lcpT + (size_t)t * (8 * 112 * 8);
    for (int c = 0; c < C_; ++c)
        base[(o * 112 + c) * 8 + jj] = f2bf(sc * __expf((row[c] - m2) * invt));
    for (int c = C_; c < 112; ++c)
        base[(o * 112 + c) * 8 + jj] = 0;
}

// ---- fused: 16 rows/wave, 8 waves/block (512 thr, 128 rows), TPG=4, NG=8.
//      Staging via global_load_lds (no prefetch VGPRs, no ds_writes):
//      swS [k8][64][8] frag-contiguous (conflict-free), lcpS exact image.
//      LDS 80,896 B -> 2 blocks/CU = 16 waves/CU (4/SIMD).
__global__ __launch_bounds__(512, 2)
void k_fused(const u16* __restrict__ xb, const u16* __restrict__ swb,
             const float* __restrict__ sb, const float* __restrict__ logT,
             const u16* __restrict__ lcpT, void* __restrict__ dst, int storeMode) {
    __shared__ __attribute__((aligned(16))) u16 swS[32 * 64 * 8];  // 32,768 B
    __shared__ __attribute__((aligned(16))) u16 lcpS[8 * 112 * 8]; // 14,336 B
    __shared__ float slog[8][16][66];                               // 33,792 B
    int tid  = threadIdx.x;
    int w    = tid >> 6;
    int lane = tid & 63;
    int col  = lane & 15;
    int quad = lane >> 4;
    int mb   = blockIdx.x * 128 + w * 16;
    int tg   = blockIdx.y;

    float temp = __expf(logT[0]);
    temp = fminf(fmaxf(temp, 0.1f), 5.0f);
    float invt = 1.0f / temp;

    // A fragments: 8 k-slices, direct bf16 loads (16 rows/wave)
    bf16x8 afr[8];
    #pragma unroll
    for (int ks = 0; ks < 8; ++ks)
        afr[ks] = *(const bf16x8*)(xb + (size_t)(mb + col) * F_ + ks * 32 + quad * 8);

    f32x4 accO[7];
    #pragma unroll
    for (int i = 0; i < 7; ++i) accO[i] = (f32x4){0.f, 0.f, 0.f, 0.f};

    #pragma unroll 1
    for (int ti = 0; ti < TPG; ++ti) {
        int t = tg * TPG + ti;

        __syncthreads();   // all waves done reading previous tile

        // stage tree t: linear global->LDS DMA (wave w fills its 1KB slices)
        {
            const char* gsw = (const char*)(swb + (size_t)t * (32 * 64 * 8));
            char* lsw = (char*)swS;
            #pragma unroll
            for (int r = 0; r < 4; ++r)
                gl16(gsw + r * 8192 + w * 1024 + lane * 16,
                     lsw + r * 8192 + w * 1024);
            const char* glc = (const char*)(lcpT + (size_t)t * (8 * 112 * 8));
            char* llc = (char*)lcpS;
            gl16(glc + w * 1024 + lane * 16, llc + w * 1024);
            if (w < 6)
                gl16(glc + 8192 + w * 1024 + lane * 16, llc + 8192 + w * 1024);
        }

        __syncthreads();   // implies vmcnt(0) drain: tile visible

        // ---- GEMM1 (swS [k8][n][8]: k8 = ks*4+quad, lanes contiguous in n)
        f32x4 acc[4];
        #pragma unroll
        for (int i = 0; i < 4; ++i) acc[i] = (f32x4){0.f, 0.f, 0.f, 0.f};
        #pragma unroll
        for (int ks = 0; ks < 8; ++ks) {
            #pragma unroll
            for (int nt = 0; nt < 4; ++nt) {
                int n  = nt * 16 + col;
                int ne = n > 62 ? 62 : n;
                bf16x8 bfr = *(const bf16x8*)&swS[((ks * 4 + quad) * 64 + ne) * 8];
                acc[nt] = __builtin_amdgcn_mfma_f32_16x16x32_bf16(afr[ks], bfr, acc[nt], 0, 0, 0);
            }
        }

        // ---- epilogue: bias+sigmoid -> slog
        asm volatile("s_waitcnt lgkmcnt(0)" ::: "memory");
        #pragma unroll
        for (int nt = 0; nt < 4; ++nt) {
            int n = nt * 16 + col;
            float bias = (n < NI_) ? sb[t * NI_ + n] : 0.f;
            #pragma unroll
            for (int r = 0; r < 4; ++r) {
                float lg = (acc[nt][r] + bias) * invt;
                slog[w][quad * 4 + r][n] = 1.0f / (1.0f + __expf(-lg));
            }
        }
        asm volatile("s_waitcnt lgkmcnt(0)" ::: "memory");

        // ---- leaf walk
        bf16x8 af0, af1;
        #pragma unroll
        for (int grp = 0; grp < 2; ++grp) {
            int s = (grp ? 11 : 7) + quad;
            float pref = 1.0f;
            int node = s;
            #pragma unroll
            for (int d = 0; d < 3; ++d) {
                int par = (node - 1) >> 1;
                float g = slog[w][col][par];
                pref = (node & 1) ? (pref - pref * g) : (pref * g);  // odd=left -> 1-g
                node = par;
            }
            float gs  = slog[w][col][s];
            float gl  = slog[w][col][2 * s + 1];
            float gr  = slog[w][col][2 * s + 2];
            float g00 = slog[w][col][4 * s + 3];
            float g01 = slog[w][col][4 * s + 4];
            float g10 = slog[w][col][4 * s + 5];
            float g11 = slog[w][col][4 * s + 6];
            #pragma unroll
            for (int j = 0; j < 8; ++j) {
                const int b2 = (j >> 2) & 1, b1 = (j >> 1) & 1, b0 = j & 1;
                float f3 = b2 ? gs : 1.0f - gs;
                float c1 = b2 ? gr : gl;
                float f4 = b1 ? c1 : 1.0f - c1;
                float c2 = b2 ? (b1 ? g11 : g10) : (b1 ? g01 : g00);
                float f5 = b0 ? c2 : 1.0f - c2;
                float p  = pref * f3 * f4 * f5;
                if (grp == 0) af0[j] = (short)f2bf(p);
                else          af1[j] = (short)f2bf(p);
            }
        }

        // ---- GEMM2
        #pragma unroll
        for (int nt = 0; nt < 7; ++nt) {
            int n = nt * 16 + col;
            bf16x8 lb0 = *(const bf16x8*)&lcpS[(quad * 112 + n) * 8];
            bf16x8 lb1 = *(const bf16x8*)&lcpS[((4 + quad) * 112 + n) * 8];
            accO[nt] = __builtin_amdgcn_mfma_f32_16x16x32_bf16(af0, lb0, accO[nt], 0, 0, 0);
            accO[nt] = __builtin_amdgcn_mfma_f32_16x16x32_bf16(af1, lb1, accO[nt], 0, 0, 0);
        }
    }

    if (storeMode) {
        // bf16 partial stores to part[tg][b][112] — no RMW, half the bytes
        u16* pp = (u16*)dst + (size_t)tg * B_ * 112;
        #pragma unroll
        for (int nt = 0; nt < 7; ++nt) {
            int c = nt * 16 + col;
            #pragma unroll
            for (int r = 0; r < 4; ++r) {
                int b = mb + quad * 4 + r;
                pp[(size_t)b * 112 + c] = f2bf(accO[nt][r]);
            }
        }
    } else {
        // atomic fallback path
        float* od = (float*)dst;
        #pragma unroll
        for (int nt = 0; nt < 7; ++nt) {
            int c = nt * 16 + col;
            if (c < C_) {
                #pragma unroll
                for (int r = 0; r < 4; ++r) {
                    int b = mb + quad * 4 + r;
                    atomicAdd(&od[(size_t)b * C_ + c], accO[nt][r]);
                }
            }
        }
    }
}

// ---- reduce: out[b][c] = sum_tg bf2f(part[tg][b][c]) ----
__global__ void k_red(const u16* __restrict__ part, float* __restrict__ out) {
    int idx = blockIdx.x * 256 + threadIdx.x;    // over B_*112
    int b = idx / 112, c = idx - b * 112;
    if (c < C_) {
        float s = 0.f;
        #pragma unroll
        for (int tg = 0; tg < NG; ++tg)
            s += bf2f(part[((size_t)tg * B_ + b) * 112 + c]);
        out[(size_t)b * C_ + c] = s;
    }
}

// ---- guard path: zero fp32 output ----
__global__ void k_zf(float* __restrict__ out, int n) {
    int i = blockIdx.x * 256 + threadIdx.x;
    if (i < n) out[i] = 0.f;
}

// ---- zero-ws fallback (R5-verified structure, fp32 I/O) ----
__global__ void k_mono(const float* __restrict__ x, const float* __restrict__ sw,
                       const float* __restrict__ sb, const float* __restrict__ ll,
                       const float* __restrict__ tw, const float* __restrict__ logT,
                       float* __restrict__ outg) {
    __shared__ float slcp[NL_ * C_];
    int tid = threadIdx.x;
    int b = blockIdx.x * 256 + tid;

    float temp = __expf(logT[0]);
    temp = fminf(fmaxf(temp, 0.1f), 5.0f);
    float invt = 1.0f / temp;

    float m = -1e30f;
    for (int j = 0; j < T_; ++j) m = fmaxf(m, tw[j]);
    float sden = 0.f;
    for (int j = 0; j < T_; ++j) sden += __expf(tw[j] - m);

    float acc[C_];
    #pragma unroll
    for (int c = 0; c < C_; ++c) acc[c] = 0.f;

    for (int t = 0; t < T_; ++t) {
        __syncthreads();
        {
            int l = tid & 63, cq = tid >> 6;
            float wt = __expf(tw[t] - m) / sden;
            const float* row = ll + ((size_t)t * NL_ + l) * C_;
            float m2 = -1e30f;
            for (int c = 0; c < C_; ++c) m2 = fmaxf(m2, row[c]);
            float s2 = 0.f;
            for (int c = 0; c < C_; ++c) s2 += __expf((row[c] - m2) * invt);
            float sc = wt / s2;
            for (int c = cq * 25; c < cq * 25 + 25; ++c)
                slcp[l * C_ + c] = sc * __expf((row[c] - m2) * invt);
        }
        __syncthreads();

        float an[NI_];
        #pragma unroll
        for (int n = 0; n < NI_; ++n) an[n] = 0.f;
        for (int k = 0; k < F_; ++k) {
            float xv = x[(size_t)b * F_ + k];
            #pragma unroll
            for (int n = 0; n < NI_; ++n)
                an[n] = fmaf(xv, sw[((size_t)t * NI_ + n) * F_ + k], an[n]);
        }
        #pragma unroll
        for (int n = 0; n < NI_; ++n) {
            float lg = (an[n] + sb[t * NI_ + n]) * invt;
            an[n] = 1.0f / (1.0f + __expf(-lg));
        }
        #pragma unroll
        for (int l = 0; l < NL_; ++l) {
            int node = l + NI_;
            float p = 1.0f;
            #pragma unroll
            for (int d = 0; d < 6; ++d) {
                int par = (node - 1) >> 1;
                float gv = an[par];
                p = (node & 1) ? (p - p * gv) : (p * gv);
                node = par;
            }
            #pragma unroll
            for (int c = 0; c < C_; ++c)
                acc[c] = fmaf(p, slcp[l * C_ + c], acc[c]);
        }
    }
    for (int c = 0; c < C_; ++c)
        outg[(size_t)b * C_ + c] = acc[c];
}

extern "C" void kernel_launch(void* const* d_in, const int* in_sizes, int n_in,
                              void* d_out, int out_size, void* d_ws, size_t ws_size,
                              hipStream_t stream) {
    bool ok = (n_in >= 6)
           && (in_sizes[0] == B_ * F_)
           && (in_sizes[1] == T_ * NI_ * F_)
           && (in_sizes[2] == T_ * NI_)
           && (in_sizes[3] == T_ * NL_ * C_)
           && (in_sizes[4] == T_)
           && (in_sizes[5] == 1)
           && (out_size == B_ * C_);
    if (!ok) {
        k_zf<<<(out_size + 255) / 256, 256, 0, stream>>>((float*)d_out, out_size);
        return;
    }

    const float* x    = (const float*)d_in[0];
    const float* sw   = (const float*)d_in[1];
    const float* sb   = (const float*)d_in[2];
    const float* ll   = (const float*)d_in[3];
    const float* tw   = (const float*)d_in[4];
    const float* logT = (const float*)d_in[5];
    float* out = (float*)d_out;

    if (ws_size >= WSB_STORE) {
        u16* swb  = (u16*)((char*)d_ws + WSB_SWB);
        u16* lcpT = (u16*)((char*)d_ws + WSB_LCPT);
        u16* xb   = (u16*)((char*)d_ws + WSB_XB);
        u16* part = (u16*)((char*)d_ws + WSB_PART);

        k_prep <<<SWBLK + XBLK + LCPBLK, 256, 0, stream>>>(sw, x, ll, tw, logT, swb, xb, lcpT, out);
        k_fused<<<dim3(B_ / 128, NG), 512, 0, stream>>>(xb, swb, sb, logT, lcpT, part, 1);
        k_red  <<<(B_ * 112) / 256, 256, 0, stream>>>(part, out);
    } else if (ws_size >= WSB_ATOM) {
        u16* swb  = (u16*)((char*)d_ws + WSB_SWB);
        u16* lcpT = (u16*)((char*)d_ws + WSB_LCPT);
        u16* xb   = (u16*)((char*)d_ws + WSB_XB);

        k_prep <<<SWBLK + XBLK + LCPBLK + ZBLK, 256, 0, stream>>>(sw, x, ll, tw, logT, swb, xb, lcpT, out);
        k_fused<<<dim3(B_ / 128, NG), 512, 0, stream>>>(xb, swb, sb, logT, lcpT, d_out, 0);
    } else {
        k_mono<<<B_ / 256, 256, 0, stream>>>(x, sw, sb, ll, tw, logT, out);
    }
}

// Round 7
// 123.642 us; speedup vs baseline: 1.0755x; 1.0755x over previous
//
#include <hip/hip_runtime.h>
#include <math.h>

#define B_  8192
#define F_  256
#define T_  32
#define NI_ 63
#define NL_ 64
#define C_  100
#define K2_ (T_*NL_)       // 2048 = GEMM2 K
#define NG  4              // tree groups
#define TPG 8              // trees per group

typedef unsigned short u16;
typedef __attribute__((ext_vector_type(8))) short bf16x8;   // MFMA A/B frag
typedef __attribute__((ext_vector_type(4))) float f32x4;    // MFMA C/D frag
typedef __attribute__((ext_vector_type(8))) unsigned short u16x8;

__device__ __forceinline__ u16 f2bf(float f) {
    unsigned int u = __float_as_uint(f);
    u += 0x7fffu + ((u >> 16) & 1u);      // RNE
    return (u16)(u >> 16);
}
__device__ __forceinline__ float bf2f(u16 u) {
    return __uint_as_float(((unsigned int)u) << 16);
}

// 16B global->LDS direct copy. LDS dest is WAVE-UNIFORM base (HW adds lane*16);
// global src is per-lane.
__device__ __forceinline__ void gl16(const void* g, void* l) {
    __builtin_amdgcn_global_load_lds(
        (const __attribute__((address_space(1))) unsigned int*)g,
        (__attribute__((address_space(3))) unsigned int*)l,
        16, 0, 0);
}

// ws layout (bytes):
//   swb2 : u16 [T_][32][64][8]  = 1,048,576   (frag-contiguous, n padded to 64)
//   lcp2 : u16 [T_][8][112][8]  =   458,752   (exact LDS tile image per tree)
//   xb   : u16 [B_][F_]         = 4,194,304
//   part : u16 [NG][B_][112]    = 7,340,032   (bf16 partials, store path)
#define WSB_SWB   0
#define WSB_LCPT  (T_*32*64*8*2)                            //  1,048,576
#define WSB_XB    (WSB_LCPT + T_*8*112*8*2)                 //  1,507,328
#define WSB_PART  ((size_t)WSB_XB + (size_t)B_*F_*2)        //  5,701,632
#define WSB_ATOM  WSB_PART                                   // atomic path total
#define WSB_STORE (WSB_PART + (size_t)NG*B_*112*2)           // 13,041,664

// ---- prep: sw -> swb2 [t][k8][64][8], x->bf16, ll -> lcp2 (+ zero section) ----
#define SWBLK  (T_*64*32/256)     // 256 blocks: (t,n,k8) with n padded to 64
#define XBLK   (B_*F_/2048)       // 1024
#define LCPBLK (T_*NL_/256)       // 8
#define ZBLK   (B_*C_/256)        // 3200

__device__ __forceinline__ void cvt8(const float* __restrict__ s, u16* __restrict__ d, int i) {
    const float4* p = (const float4*)(s + i);
    float4 v0 = p[0], v1 = p[1];
    u16x8 o;
    o[0] = f2bf(v0.x); o[1] = f2bf(v0.y); o[2] = f2bf(v0.z); o[3] = f2bf(v0.w);
    o[4] = f2bf(v1.x); o[5] = f2bf(v1.y); o[6] = f2bf(v1.z); o[7] = f2bf(v1.w);
    *(u16x8*)(d + i) = o;
}

__global__ void k_prep(const float* __restrict__ sw, const float* __restrict__ x,
                       const float* __restrict__ ll, const float* __restrict__ tw,
                       const float* __restrict__ logT,
                       u16* __restrict__ swb, u16* __restrict__ xb,
                       u16* __restrict__ lcpT, float* __restrict__ out) {
    int blk = blockIdx.x, tid = threadIdx.x;
    if (blk < SWBLK) {
        // gid -> (t, n(0..63), k8(0..31)); read sw[t][n][k8*8..+8], write
        // swb2[((t*32+k8)*64+n)*8..+8]; n==63 is the pad row (zeros).
        int gid = blk * 256 + tid;
        int k8 = gid & 31;
        int n  = (gid >> 5) & 63;
        int t  = gid >> 11;
        u16x8 o;
        if (n < NI_) {
            const float4* p = (const float4*)(sw + ((size_t)(t * NI_ + n)) * F_ + k8 * 8);
            float4 v0 = p[0], v1 = p[1];
            o[0] = f2bf(v0.x); o[1] = f2bf(v0.y); o[2] = f2bf(v0.z); o[3] = f2bf(v0.w);
            o[4] = f2bf(v1.x); o[5] = f2bf(v1.y); o[6] = f2bf(v1.z); o[7] = f2bf(v1.w);
        } else {
            o = (u16x8){0,0,0,0,0,0,0,0};
        }
        *(u16x8*)(swb + (((size_t)t * 32 + k8) * 64 + n) * 8) = o;
        return;
    }
    blk -= SWBLK;
    if (blk < XBLK) { cvt8(x, xb, blk * 2048 + tid * 8); return; }
    blk -= XBLK;
    if (blk >= LCPBLK) {                    // zero section (atomic path only)
        out[(blk - LCPBLK) * 256 + tid] = 0.f;
        return;
    }
    int idx = blk * 256 + tid;              // leaf row: t*64 + l
    int t = idx >> 6;
    int l = idx & 63;
    int o = l >> 3, jj = l & 7;
    float temp = __expf(logT[0]);
    temp = fminf(fmaxf(temp, 0.1f), 5.0f);
    float invt = 1.0f / temp;

    float m = -1e30f;
    for (int j = 0; j < T_; ++j) m = fmaxf(m, tw[j]);
    float s = 0.f;
    for (int j = 0; j < T_; ++j) s += __expf(tw[j] - m);
    float wt = __expf(tw[t] - m) / s;

    const float* row = ll + (size_t)idx * C_;
    float m2 = -1e30f;
    for (int c = 0; c < C_; ++c) m2 = fmaxf(m2, row[c]);
    float s2 = 0.f;
    for (int c = 0; c < C_; ++c) s2 += __expf((row[c] - m2) * invt);
    float sc = wt / s2;
    u16* base = lcpT + (size_t)t * (8 * 112 * 8);
    for (int c = 0; c < C_; ++c)
        base[(o * 112 + c) * 8 + jj] = f2bf(sc * __expf((row[c] - m2) * invt));
    for (int c = C_; c < 112; ++c)
        base[(o * 112 + c) * 8 + jj] = 0;
}

// stage one tree's tiles into (swsD, lcpD) via global_load_lds; issue-only,
// no wait. LDS dest bases are wave-uniform; lane*16 is the per-lane global src.
__device__ __forceinline__ void stage_tree(const u16* __restrict__ swb,
                                           const u16* __restrict__ lcpT,
                                           u16* swsD, u16* lcpD,
                                           int t, int w, int lane) {
    const char* gsw = (const char*)(swb + (size_t)t * (32 * 64 * 8));
    char* lsw = (char*)swsD;
    #pragma unroll
    for (int r = 0; r < 4; ++r)
        gl16(gsw + r * 8192 + w * 1024 + lane * 16,
             lsw + r * 8192 + w * 1024);
    const char* glc = (const char*)(lcpT + (size_t)t * (8 * 112 * 8));
    char* llc = (char*)lcpD;
    gl16(glc + w * 1024 + lane * 16, llc + w * 1024);
    if (w < 6)
        gl16(glc + 8192 + w * 1024 + lane * 16, llc + 8192 + w * 1024);
}

// ---- fused: 16 rows/wave, 8 waves/block (512 thr, 128 rows), TPG=8, NG=4.
//      Double-buffered gl_lds staging: ONE barrier per tree; stage(t+1) issued
//      right after the barrier overlaps compute(t). LDS 128,000 B -> 1 block/CU
//      (8 waves = 2/SIMD) with near-zero exposed staging latency.
__global__ __launch_bounds__(512, 2)
void k_fused(const u16* __restrict__ xb, const u16* __restrict__ swb,
             const float* __restrict__ sb, const float* __restrict__ logT,
             const u16* __restrict__ lcpT, void* __restrict__ dst, int storeMode) {
    __shared__ __attribute__((aligned(16))) u16 swS[2][32 * 64 * 8];  // 65,536 B
    __shared__ __attribute__((aligned(16))) u16 lcpS[2][8 * 112 * 8]; // 28,672 B
    __shared__ float slog[8][16][66];                                  // 33,792 B
    int tid  = threadIdx.x;
    int w    = tid >> 6;
    int lane = tid & 63;
    int col  = lane & 15;
    int quad = lane >> 4;
    int mb   = blockIdx.x * 128 + w * 16;
    int tg   = blockIdx.y;

    float temp = __expf(logT[0]);
    temp = fminf(fmaxf(temp, 0.1f), 5.0f);
    float invt = 1.0f / temp;

    // A fragments: 8 k-slices, direct bf16 loads (16 rows/wave)
    bf16x8 afr[8];
    #pragma unroll
    for (int ks = 0; ks < 8; ++ks)
        afr[ks] = *(const bf16x8*)(xb + (size_t)(mb + col) * F_ + ks * 32 + quad * 8);

    // prologue: stage tile 0 into buffer 0
    stage_tree(swb, lcpT, swS[0], lcpS[0], tg * TPG, w, lane);

    f32x4 accO[7];
    #pragma unroll
    for (int i = 0; i < 7; ++i) accO[i] = (f32x4){0.f, 0.f, 0.f, 0.f};

    int cur = 0;
    #pragma unroll 1
    for (int ti = 0; ti < TPG; ++ti) {
        int t = tg * TPG + ti;

        asm volatile("s_waitcnt vmcnt(0)" ::: "memory");  // my DMA for buf[cur] done
        __syncthreads();                                   // everyone's done -> tile visible

        if (ti + 1 < TPG)   // overlap: stage next tree into the other buffer
            stage_tree(swb, lcpT, swS[cur ^ 1], lcpS[cur ^ 1], t + 1, w, lane);

        const u16* sws  = swS[cur];
        const u16* lcps = lcpS[cur];

        // ---- GEMM1 (sws [k8][n][8]: k8 = ks*4+quad, lanes contiguous in n)
        f32x4 acc[4];
        #pragma unroll
        for (int i = 0; i < 4; ++i) acc[i] = (f32x4){0.f, 0.f, 0.f, 0.f};
        #pragma unroll
        for (int ks = 0; ks < 8; ++ks) {
            #pragma unroll
            for (int nt = 0; nt < 4; ++nt) {
                int n  = nt * 16 + col;
                int ne = n > 62 ? 62 : n;
                bf16x8 bfr = *(const bf16x8*)&sws[((ks * 4 + quad) * 64 + ne) * 8];
                acc[nt] = __builtin_amdgcn_mfma_f32_16x16x32_bf16(afr[ks], bfr, acc[nt], 0, 0, 0);
            }
        }

        // ---- epilogue: bias+sigmoid -> slog
        asm volatile("s_waitcnt lgkmcnt(0)" ::: "memory");
        #pragma unroll
        for (int nt = 0; nt < 4; ++nt) {
            int n = nt * 16 + col;
            float bias = (n < NI_) ? sb[t * NI_ + n] : 0.f;
            #pragma unroll
            for (int r = 0; r < 4; ++r) {
                float lg = (acc[nt][r] + bias) * invt;
                slog[w][quad * 4 + r][n] = 1.0f / (1.0f + __expf(-lg));
            }
        }
        asm volatile("s_waitcnt lgkmcnt(0)" ::: "memory");

        // ---- leaf walk
        bf16x8 af0, af1;
        #pragma unroll
        for (int grp = 0; grp < 2; ++grp) {
            int s = (grp ? 11 : 7) + quad;
            float pref = 1.0f;
            int node = s;
            #pragma unroll
            for (int d = 0; d < 3; ++d) {
                int par = (node - 1) >> 1;
                float g = slog[w][col][par];
                pref = (node & 1) ? (pref - pref * g) : (pref * g);  // odd=left -> 1-g
                node = par;
            }
            float gs  = slog[w][col][s];
            float gl  = slog[w][col][2 * s + 1];
            float gr  = slog[w][col][2 * s + 2];
            float g00 = slog[w][col][4 * s + 3];
            float g01 = slog[w][col][4 * s + 4];
            float g10 = slog[w][col][4 * s + 5];
            float g11 = slog[w][col][4 * s + 6];
            #pragma unroll
            for (int j = 0; j < 8; ++j) {
                const int b2 = (j >> 2) & 1, b1 = (j >> 1) & 1, b0 = j & 1;
                float f3 = b2 ? gs : 1.0f - gs;
                float c1 = b2 ? gr : gl;
                float f4 = b1 ? c1 : 1.0f - c1;
                float c2 = b2 ? (b1 ? g11 : g10) : (b1 ? g01 : g00);
                float f5 = b0 ? c2 : 1.0f - c2;
                float p  = pref * f3 * f4 * f5;
                if (grp == 0) af0[j] = (short)f2bf(p);
                else          af1[j] = (short)f2bf(p);
            }
        }

        // ---- GEMM2
        #pragma unroll
        for (int nt = 0; nt < 7; ++nt) {
            int n = nt * 16 + col;
            bf16x8 lb0 = *(const bf16x8*)&lcps[(quad * 112 + n) * 8];
            bf16x8 lb1 = *(const bf16x8*)&lcps[((4 + quad) * 112 + n) * 8];
            accO[nt] = __builtin_amdgcn_mfma_f32_16x16x32_bf16(af0, lb0, accO[nt], 0, 0, 0);
            accO[nt] = __builtin_amdgcn_mfma_f32_16x16x32_bf16(af1, lb1, accO[nt], 0, 0, 0);
        }

        cur ^= 1;
    }

    if (storeMode) {
        // bf16 partial stores to part[tg][b][112] — no RMW, half the bytes
        u16* pp = (u16*)dst + (size_t)tg * B_ * 112;
        #pragma unroll
        for (int nt = 0; nt < 7; ++nt) {
            int c = nt * 16 + col;
            #pragma unroll
            for (int r = 0; r < 4; ++r) {
                int b = mb + quad * 4 + r;
                pp[(size_t)b * 112 + c] = f2bf(accO[nt][r]);
            }
        }
    } else {
        // atomic fallback path
        float* od = (float*)dst;
        #pragma unroll
        for (int nt = 0; nt < 7; ++nt) {
            int c = nt * 16 + col;
            if (c < C_) {
                #pragma unroll
                for (int r = 0; r < 4; ++r) {
                    int b = mb + quad * 4 + r;
                    atomicAdd(&od[(size_t)b * C_ + c], accO[nt][r]);
                }
            }
        }
    }
}

// ---- reduce: out[b][c] = sum_tg bf2f(part[tg][b][c]) ----
__global__ void k_red(const u16* __restrict__ part, float* __restrict__ out) {
    int idx = blockIdx.x * 256 + threadIdx.x;    // over B_*112
    int b = idx / 112, c = idx - b * 112;
    if (c < C_) {
        float s = 0.f;
        #pragma unroll
        for (int tg = 0; tg < NG; ++tg)
            s += bf2f(part[((size_t)tg * B_ + b) * 112 + c]);
        out[(size_t)b * C_ + c] = s;
    }
}

// ---- guard path: zero fp32 output ----
__global__ void k_zf(float* __restrict__ out, int n) {
    int i = blockIdx.x * 256 + threadIdx.x;
    if (i < n) out[i] = 0.f;
}

// ---- zero-ws fallback (R5-verified structure, fp32 I/O) ----
__global__ void k_mono(const float* __restrict__ x, const float* __restrict__ sw,
                       const float* __restrict__ sb, const float* __restrict__ ll,
                       const float* __restrict__ tw, const float* __restrict__ logT,
                       float* __restrict__ outg) {
    __shared__ float slcp[NL_ * C_];
    int tid = threadIdx.x;
    int b = blockIdx.x * 256 + tid;

    float temp = __expf(logT[0]);
    temp = fminf(fmaxf(temp, 0.1f), 5.0f);
    float invt = 1.0f / temp;

    float m = -1e30f;
    for (int j = 0; j < T_; ++j) m = fmaxf(m, tw[j]);
    float sden = 0.f;
    for (int j = 0; j < T_; ++j) sden += __expf(tw[j] - m);

    float acc[C_];
    #pragma unroll
    for (int c = 0; c < C_; ++c) acc[c] = 0.f;

    for (int t = 0; t < T_; ++t) {
        __syncthreads();
        {
            int l = tid & 63, cq = tid >> 6;
            float wt = __expf(tw[t] - m) / sden;
            const float* row = ll + ((size_t)t * NL_ + l) * C_;
            float m2 = -1e30f;
            for (int c = 0; c < C_; ++c) m2 = fmaxf(m2, row[c]);
            float s2 = 0.f;
            for (int c = 0; c < C_; ++c) s2 += __expf((row[c] - m2) * invt);
            float sc = wt / s2;
            for (int c = cq * 25; c < cq * 25 + 25; ++c)
                slcp[l * C_ + c] = sc * __expf((row[c] - m2) * invt);
        }
        __syncthreads();

        float an[NI_];
        #pragma unroll
        for (int n = 0; n < NI_; ++n) an[n] = 0.f;
        for (int k = 0; k < F_; ++k) {
            float xv = x[(size_t)b * F_ + k];
            #pragma unroll
            for (int n = 0; n < NI_; ++n)
                an[n] = fmaf(xv, sw[((size_t)t * NI_ + n) * F_ + k], an[n]);
        }
        #pragma unroll
        for (int n = 0; n < NI_; ++n) {
            float lg = (an[n] + sb[t * NI_ + n]) * invt;
            an[n] = 1.0f / (1.0f + __expf(-lg));
        }
        #pragma unroll
        for (int l = 0; l < NL_; ++l) {
            int node = l + NI_;
            float p = 1.0f;
            #pragma unroll
            for (int d = 0; d < 6; ++d) {
                int par = (node - 1) >> 1;
                float gv = an[par];
                p = (node & 1) ? (p - p * gv) : (p * gv);
                node = par;
            }
            #pragma unroll
            for (int c = 0; c < C_; ++c)
                acc[c] = fmaf(p, slcp[l * C_ + c], acc[c]);
        }
    }
    for (int c = 0; c < C_; ++c)
        outg[(size_t)b * C_ + c] = acc[c];
}

extern "C" void kernel_launch(void* const* d_in, const int* in_sizes, int n_in,
                              void* d_out, int out_size, void* d_ws, size_t ws_size,
                              hipStream_t stream) {
    bool ok = (n_in >= 6)
           && (in_sizes[0] == B_ * F_)
           && (in_sizes[1] == T_ * NI_ * F_)
           && (in_sizes[2] == T_ * NI_)
           && (in_sizes[3] == T_ * NL_ * C_)
           && (in_sizes[4] == T_)
           && (in_sizes[5] == 1)
           && (out_size == B_ * C_);
    if (!ok) {
        k_zf<<<(out_size + 255) / 256, 256, 0, stream>>>((float*)d_out, out_size);
        return;
    }

    const float* x    = (const float*)d_in[0];
    const float* sw   = (const float*)d_in[1];
    const float* sb   = (const float*)d_in[2];
    const float* ll   = (const float*)d_in[3];
    const float* tw   = (const float*)d_in[4];
    const float* logT = (const float*)d_in[5];
    float* out = (float*)d_out;

    if (ws_size >= WSB_STORE) {
        u16* swb  = (u16*)((char*)d_ws + WSB_SWB);
        u16* lcpT = (u16*)((char*)d_ws + WSB_LCPT);
        u16* xb   = (u16*)((char*)d_ws + WSB_XB);
        u16* part = (u16*)((char*)d_ws + WSB_PART);

        k_prep <<<SWBLK + XBLK + LCPBLK, 256, 0, stream>>>(sw, x, ll, tw, logT, swb, xb, lcpT, out);
        k_fused<<<dim3(B_ / 128, NG), 512, 0, stream>>>(xb, swb, sb, logT, lcpT, part, 1);
        k_red  <<<(B_ * 112) / 256, 256, 0, stream>>>(part, out);
    } else if (ws_size >= WSB_ATOM) {
        u16* swb  = (u16*)((char*)d_ws + WSB_SWB);
        u16* lcpT = (u16*)((char*)d_ws + WSB_LCPT);
        u16* xb   = (u16*)((char*)d_ws + WSB_XB);

        k_prep <<<SWBLK + XBLK + LCPBLK + ZBLK, 256, 0, stream>>>(sw, x, ll, tw, logT, swb, xb, lcpT, out);
        k_fused<<<dim3(B_ / 128, NG), 512, 0, stream>>>(xb, swb, sb, logT, lcpT, d_out, 0);
    } else {
        k_mono<<<B_ / 256, 256, 0, stream>>>(x, sw, sb, ll, tw, logT, out);
    }
}